// Round 1
// baseline (284.378 us; speedup 1.0000x reference)
//
#include <hip/hip_runtime.h>

typedef __bf16 bf16x8 __attribute__((ext_vector_type(8)));
typedef float f32x4 __attribute__((ext_vector_type(4)));
typedef unsigned short u16x8 __attribute__((ext_vector_type(8)));

#define DEVI static __device__ __forceinline__

DEVI unsigned short f2b(float x) {
  unsigned u = __builtin_bit_cast(unsigned, x);
  unsigned r = (u + 0x7FFFu + ((u >> 16) & 1u)) >> 16;
  return (unsigned short)r;
}
DEVI float b2f(unsigned short b) {
  unsigned u = ((unsigned)b) << 16;
  return __builtin_bit_cast(float, u);
}

// Pre-pack W2 (and W2^T) into per-lane MFMA B-fragment order, bf16.
// Fragment f covers k-step t1 (32 k's) x 16 cols (t0). Element layout per lane l:
// B[k = t1*32 + (l>>4)*8 + j][c = t0*16 + (l&15)], j contiguous -> one 16B load/lane.
__global__ __launch_bounds__(256) void pack_w2_kernel(
    const float* __restrict__ W2, unsigned short* __restrict__ p1,
    unsigned short* __restrict__ p2) {
  int idx = blockIdx.x * 256 + threadIdx.x;   // 0 .. 524287
  int which = idx >> 18;
  int i = idx & 262143;
  int j = i & 7;
  int l = (i >> 3) & 63;
  int t0 = (i >> 9) & 31;   // 16-col tile
  int t1 = i >> 14;         // 32-row (k) step
  if (which == 0) {
    // GEMM1 B = W2[k][c]
    p1[i] = f2b(W2[(t1 * 32 + (l >> 4) * 8 + j) * 512 + t0 * 16 + (l & 15)]);
  } else {
    // GEMM2 B = W2^T[c][k] = W2[k][c] with roles swapped
    p2[i] = f2b(W2[(t0 * 16 + (l & 15)) * 512 + t1 * 32 + (l >> 4) * 8 + j]);
  }
}

__global__ __launch_bounds__(256, 1) void phm_kernel(
    const float* __restrict__ state, const float* __restrict__ action_emb,
    const float* __restrict__ W1, const float* __restrict__ b1,
    const float* __restrict__ b2, const float* __restrict__ W3,
    const float* __restrict__ log_damping, const float* __restrict__ Gw,
    const float* __restrict__ Gb, const unsigned short* __restrict__ packB1,
    const unsigned short* __restrict__ packB2, float* __restrict__ out) {
  __shared__ unsigned short h1s[64 * 512];   // 64KB, swizzled row-major bf16
  __shared__ unsigned short dz2s[64 * 512];  // 64KB
  __shared__ float W1s[1024];
  __shared__ float b1s[512];
  __shared__ float b2s[512];
  __shared__ float W3s[512];
  __shared__ float st[128];
  __shared__ float part[4][64][2];

  const int t = threadIdx.x;
  const int lane = t & 63;
  const int wid = t >> 6;
  const int l15 = lane & 15;
  const int l4 = lane >> 4;
  const long row0 = (long)blockIdx.x * 64;
  const f32x4 fzero = {0.f, 0.f, 0.f, 0.f};

  // ---- stage small tables ----
  for (int i = t; i < 512; i += 256) {
    W1s[i] = W1[i];
    W1s[512 + i] = W1[512 + i];
    b1s[i] = b1[i];
    b2s[i] = b2[i];
    W3s[i] = W3[i];
  }
  if (t < 128) st[t] = state[row0 * 2 + t];
  __syncthreads();

  // ---- phase 0: h1 = softplus(state @ W1 + b1) -> LDS bf16 (swizzled) ----
  for (int it = 0; it < 16; ++it) {
    int gid = it * 256 + t;
    int r = gid >> 6;      // 0..63
    int cg = gid & 63;     // 8-col group
    float s0 = st[r * 2], s1 = st[r * 2 + 1];
    u16x8 pk;
#pragma unroll
    for (int j = 0; j < 8; ++j) {
      int c = cg * 8 + j;
      float z = fmaf(s0, W1s[c], fmaf(s1, W1s[512 + c], b1s[c]));
      float e = __expf(-fabsf(z));
      float h = fmaxf(z, 0.f) + __logf(1.f + e);
      pk[j] = f2b(h);
    }
    int bo = (cg * 16) ^ ((r & 15) << 4);
    *reinterpret_cast<u16x8*>(reinterpret_cast<char*>(h1s) + r * 1024 + bo) = pk;
  }
  __syncthreads();

  // ---- GEMM1: z2 = h1 @ W2 ; dz2 = W3 * sigmoid(z2 + b2) -> LDS ----
  // Waves split columns: wave strip = 128 cols, 2 chunks of 64.
  for (int chunk = 0; chunk < 2; ++chunk) {
    const int c0 = wid * 128 + chunk * 64;
    f32x4 acc[4][4];
#pragma unroll
    for (int a = 0; a < 4; ++a)
#pragma unroll
      for (int b = 0; b < 4; ++b) acc[a][b] = fzero;

#pragma unroll 2
    for (int kt = 0; kt < 16; ++kt) {
      bf16x8 af[4];
      int bo = (kt * 64 + l4 * 16) ^ (l15 << 4);
#pragma unroll
      for (int rt = 0; rt < 4; ++rt) {
        int rr = rt * 16 + l15;
        af[rt] = __builtin_bit_cast(
            bf16x8, *reinterpret_cast<const int4*>(
                        reinterpret_cast<const char*>(h1s) + rr * 1024 + bo));
      }
      bf16x8 bfr[4];
#pragma unroll
      for (int ct = 0; ct < 4; ++ct) {
        int frag = kt * 32 + (c0 >> 4) + ct;
        bfr[ct] = __builtin_bit_cast(
            bf16x8,
            *reinterpret_cast<const int4*>(packB1 + (frag * 64 + lane) * 8));
      }
#pragma unroll
      for (int rt = 0; rt < 4; ++rt)
#pragma unroll
        for (int ct = 0; ct < 4; ++ct)
          acc[rt][ct] = __builtin_amdgcn_mfma_f32_16x16x32_bf16(
              af[rt], bfr[ct], acc[rt][ct], 0, 0, 0);
    }
    // epilogue: C/D layout col = l&15, row = (l>>4)*4 + j  [m89-verified]
#pragma unroll
    for (int ct = 0; ct < 4; ++ct) {
      int c = c0 + ct * 16 + l15;
      float w3 = W3s[c], bb = b2s[c];
#pragma unroll
      for (int rt = 0; rt < 4; ++rt) {
#pragma unroll
        for (int j = 0; j < 4; ++j) {
          int r = rt * 16 + l4 * 4 + j;
          float z2 = acc[rt][ct][j] + bb;
          float sg = __builtin_amdgcn_rcpf(1.f + __expf(-z2));
          unsigned short u = f2b(w3 * sg);
          int bo = (c * 2) ^ ((r & 15) << 4);
          *reinterpret_cast<unsigned short*>(
              reinterpret_cast<char*>(dz2s) + r * 1024 + bo) = u;
        }
      }
    }
  }
  __syncthreads();

  // ---- GEMM2: dh1 = dz2 @ W2^T ; dz1 = dh1 * sigmoid(z1); ds = dz1 @ W1^T ----
  float p0[16], p1v[16];
#pragma unroll
  for (int i = 0; i < 16; ++i) { p0[i] = 0.f; p1v[i] = 0.f; }

  for (int chunk = 0; chunk < 2; ++chunk) {
    const int k0c = wid * 128 + chunk * 64;   // output h-columns
    f32x4 acc[4][4];
#pragma unroll
    for (int a = 0; a < 4; ++a)
#pragma unroll
      for (int b = 0; b < 4; ++b) acc[a][b] = fzero;

#pragma unroll 2
    for (int ct2 = 0; ct2 < 16; ++ct2) {   // reduction over c
      bf16x8 af[4];
      int bo = (ct2 * 64 + l4 * 16) ^ (l15 << 4);
#pragma unroll
      for (int rt = 0; rt < 4; ++rt) {
        int rr = rt * 16 + l15;
        af[rt] = __builtin_bit_cast(
            bf16x8, *reinterpret_cast<const int4*>(
                        reinterpret_cast<const char*>(dz2s) + rr * 1024 + bo));
      }
      bf16x8 bfr[4];
#pragma unroll
      for (int kt = 0; kt < 4; ++kt) {
        int frag = ct2 * 32 + (k0c >> 4) + kt;
        bfr[kt] = __builtin_bit_cast(
            bf16x8,
            *reinterpret_cast<const int4*>(packB2 + (frag * 64 + lane) * 8));
      }
#pragma unroll
      for (int rt = 0; rt < 4; ++rt)
#pragma unroll
        for (int kt = 0; kt < 4; ++kt)
          acc[rt][kt] = __builtin_amdgcn_mfma_f32_16x16x32_bf16(
              af[rt], bfr[kt], acc[rt][kt], 0, 0, 0);
    }
    // epilogue: sigmoid(z1) = 1 - exp(-h1) (h1 from LDS), accumulate ds partials
#pragma unroll
    for (int kt = 0; kt < 4; ++kt) {
      int kc = k0c + kt * 16 + l15;
      float w10 = W1s[kc], w11 = W1s[512 + kc];
#pragma unroll
      for (int rt = 0; rt < 4; ++rt) {
#pragma unroll
        for (int j = 0; j < 4; ++j) {
          int r = rt * 16 + l4 * 4 + j;
          int bo = (kc * 2) ^ ((r & 15) << 4);
          float h = b2f(*reinterpret_cast<const unsigned short*>(
              reinterpret_cast<const char*>(h1s) + r * 1024 + bo));
          float sg = 1.f - __expf(-h);
          float dz1 = acc[rt][kt][j] * sg;
          p0[rt * 4 + j] = fmaf(dz1, w10, p0[rt * 4 + j]);
          p1v[rt * 4 + j] = fmaf(dz1, w11, p1v[rt * 4 + j]);
        }
      }
    }
  }

  // reduce partials across the 16 lanes of each row-group
#pragma unroll
  for (int i = 0; i < 16; ++i) {
    float a = p0[i], b = p1v[i];
    for (int m = 1; m < 16; m <<= 1) {
      a += __shfl_xor(a, m, 64);
      b += __shfl_xor(b, m, 64);
    }
    p0[i] = a;
    p1v[i] = b;
  }
  if (l15 == 0) {
#pragma unroll
    for (int rt = 0; rt < 4; ++rt)
#pragma unroll
      for (int j = 0; j < 4; ++j) {
        int r = rt * 16 + l4 * 4 + j;
        part[wid][r][0] = p0[rt * 4 + j];
        part[wid][r][1] = p1v[rt * 4 + j];
      }
  }
  __syncthreads();

  // ---- final: combine waves, damping + action term, write (B,2) ----
  if (t < 64) {
    long grow = row0 + t;
    float g0 = part[0][t][0] + part[1][t][0] + part[2][t][0] + part[3][t][0];
    float g1 = part[0][t][1] + part[1][t][1] + part[2][t][1] + part[3][t][1];
    const float4 ae0 = reinterpret_cast<const float4*>(action_emb)[grow * 2];
    const float4 ae1 = reinterpret_cast<const float4*>(action_emb)[grow * 2 + 1];
    float gu = Gb[0];
    gu = fmaf(ae0.x, Gw[0], gu);
    gu = fmaf(ae0.y, Gw[1], gu);
    gu = fmaf(ae0.z, Gw[2], gu);
    gu = fmaf(ae0.w, Gw[3], gu);
    gu = fmaf(ae1.x, Gw[4], gu);
    gu = fmaf(ae1.y, Gw[5], gu);
    gu = fmaf(ae1.z, Gw[6], gu);
    gu = fmaf(ae1.w, Gw[7], gu);
    float damping = __expf(log_damping[0]);
    float2 o;
    o.x = g1;                              // dq_dt = dH_dp
    o.y = -g0 - damping * g1 + gu;         // dp_dt
    reinterpret_cast<float2*>(out)[grow] = o;
  }
}

extern "C" void kernel_launch(void* const* d_in, const int* in_sizes, int n_in,
                              void* d_out, int out_size, void* d_ws,
                              size_t ws_size, hipStream_t stream) {
  // setup_inputs order: t, state, action_emb, W1, b1, W2, b2, W3, b3,
  //                     log_damping, Gw, Gb
  const float* state = (const float*)d_in[1];
  const float* action_emb = (const float*)d_in[2];
  const float* W1 = (const float*)d_in[3];
  const float* b1 = (const float*)d_in[4];
  const float* W2 = (const float*)d_in[5];
  const float* b2 = (const float*)d_in[6];
  const float* W3 = (const float*)d_in[7];
  const float* log_damping = (const float*)d_in[9];
  const float* Gw = (const float*)d_in[10];
  const float* Gb = (const float*)d_in[11];
  float* out = (float*)d_out;

  unsigned short* p1 = (unsigned short*)d_ws;       // 512KB packed W2
  unsigned short* p2 = p1 + 262144;                 // 512KB packed W2^T

  pack_w2_kernel<<<dim3(2048), dim3(256), 0, stream>>>(W2, p1, p2);
  phm_kernel<<<dim3(2048), dim3(256), 0, stream>>>(
      state, action_emb, W1, b1, b2, W3, log_damping, Gw, Gb, p1, p2, out);
}

// Round 2
// 177.459 us; speedup vs baseline: 1.6025x; 1.6025x over previous
//
#include <hip/hip_runtime.h>

typedef __bf16 bf16x8 __attribute__((ext_vector_type(8)));
typedef float f32x4 __attribute__((ext_vector_type(4)));
typedef unsigned short u16x8 __attribute__((ext_vector_type(8)));

#define DEVI static __device__ __forceinline__

DEVI unsigned short f2b(float x) {
  __bf16 b = (__bf16)x;           // native v_cvt on gfx950, RNE
  return __builtin_bit_cast(unsigned short, b);
}

// Pre-pack W2 (and W2^T) into per-lane MFMA B-fragment order, bf16.
// Fragment f covers k-step t1 (32 k's) x 16 cols (t0). Element layout per lane l:
// B[k = t1*32 + (l>>4)*8 + j][c = t0*16 + (l&15)], j contiguous -> one 16B load/lane.
__global__ __launch_bounds__(256) void pack_w2_kernel(
    const float* __restrict__ W2, unsigned short* __restrict__ p1,
    unsigned short* __restrict__ p2) {
  int idx = blockIdx.x * 256 + threadIdx.x;   // 0 .. 524287
  int which = idx >> 18;
  int i = idx & 262143;
  int j = i & 7;
  int l = (i >> 3) & 63;
  int t0 = (i >> 9) & 31;   // 16-col tile
  int t1 = i >> 14;         // 32-row (k) step
  if (which == 0) {
    p1[i] = f2b(W2[(t1 * 32 + (l >> 4) * 8 + j) * 512 + t0 * 16 + (l & 15)]);
  } else {
    p2[i] = f2b(W2[(t0 * 16 + (l & 15)) * 512 + t1 * 32 + (l >> 4) * 8 + j]);
  }
}

__global__ __launch_bounds__(256, 2) void phm_kernel(
    const float* __restrict__ state, const float* __restrict__ action_emb,
    const float* __restrict__ W1, const float* __restrict__ b1,
    const float* __restrict__ b2, const float* __restrict__ W3,
    const float* __restrict__ log_damping, const float* __restrict__ Gw,
    const float* __restrict__ Gb, const unsigned short* __restrict__ packB1,
    const unsigned short* __restrict__ packB2, float* __restrict__ out) {
  // Single 64KB buffer: holds h1 (bf16, swizzled) during GEMM1, then is
  // overwritten with dz2 for GEMM2. sigmoid(z1) is recomputed from state/W1
  // in the GEMM2 epilogue, so h1 need not survive.
  __shared__ unsigned short buf[64 * 512];   // 64KB
  __shared__ float W1s[1024];
  __shared__ float b1s[512];
  __shared__ float b2s[512];
  __shared__ float W3s[512];
  __shared__ float st[128];
  __shared__ float part[4][64][2];

  const int t = threadIdx.x;
  const int lane = t & 63;
  const int wid = t >> 6;
  const int l15 = lane & 15;
  const int l4 = lane >> 4;
  const long row0 = (long)blockIdx.x * 64;
  const f32x4 fzero = {0.f, 0.f, 0.f, 0.f};

  // ---- stage small tables ----
  for (int i = t; i < 512; i += 256) {
    W1s[i] = W1[i];
    W1s[512 + i] = W1[512 + i];
    b1s[i] = b1[i];
    b2s[i] = b2[i];
    W3s[i] = W3[i];
  }
  if (t < 128) st[t] = state[row0 * 2 + t];
  __syncthreads();

  // ---- phase 0: h1 = softplus(state @ W1 + b1) -> buf bf16 (swizzled) ----
  for (int it = 0; it < 16; ++it) {
    int gid = it * 256 + t;
    int r = gid >> 6;      // 0..63
    int cg = gid & 63;     // 8-col group
    float s0 = st[r * 2], s1 = st[r * 2 + 1];
    u16x8 pk;
#pragma unroll
    for (int j = 0; j < 8; ++j) {
      int c = cg * 8 + j;
      float z = fmaf(s0, W1s[c], fmaf(s1, W1s[512 + c], b1s[c]));
      float e = __expf(-fabsf(z));
      float h = fmaxf(z, 0.f) + __logf(1.f + e);
      pk[j] = f2b(h);
    }
    int bo = (cg * 16) ^ ((r & 15) << 4);
    *reinterpret_cast<u16x8*>(reinterpret_cast<char*>(buf) + r * 1024 + bo) = pk;
  }
  __syncthreads();

  // ---- GEMM1: z2 = h1 @ W2 (both 64-col chunks held in registers) ----
  f32x4 acc1[2][4][4];
#pragma unroll
  for (int ch = 0; ch < 2; ++ch)
#pragma unroll
    for (int a = 0; a < 4; ++a)
#pragma unroll
      for (int b = 0; b < 4; ++b) acc1[ch][a][b] = fzero;

#pragma unroll
  for (int chunk = 0; chunk < 2; ++chunk) {
    const int c0 = wid * 128 + chunk * 64;
#pragma unroll 2
    for (int kt = 0; kt < 16; ++kt) {
      bf16x8 af[4];
      int bo = (kt * 64 + l4 * 16) ^ (l15 << 4);
#pragma unroll
      for (int rt = 0; rt < 4; ++rt) {
        int rr = rt * 16 + l15;
        af[rt] = __builtin_bit_cast(
            bf16x8, *reinterpret_cast<const int4*>(
                        reinterpret_cast<const char*>(buf) + rr * 1024 + bo));
      }
      bf16x8 bfr[4];
#pragma unroll
      for (int ct = 0; ct < 4; ++ct) {
        int frag = kt * 32 + (c0 >> 4) + ct;
        bfr[ct] = __builtin_bit_cast(
            bf16x8,
            *reinterpret_cast<const int4*>(packB1 + (frag * 64 + lane) * 8));
      }
#pragma unroll
      for (int rt = 0; rt < 4; ++rt)
#pragma unroll
        for (int ct = 0; ct < 4; ++ct)
          acc1[chunk][rt][ct] = __builtin_amdgcn_mfma_f32_16x16x32_bf16(
              af[rt], bfr[ct], acc1[chunk][rt][ct], 0, 0, 0);
    }
  }
  __syncthreads();   // every wave done reading h1 from buf

  // ---- GEMM1 epilogue: dz2 = W3 * sigmoid(z2 + b2) -> overwrite buf ----
  // C/D layout: col = l&15, row = (l>>4)*4 + j  [m89-verified]
#pragma unroll
  for (int chunk = 0; chunk < 2; ++chunk) {
    const int c0 = wid * 128 + chunk * 64;
#pragma unroll
    for (int ct = 0; ct < 4; ++ct) {
      int c = c0 + ct * 16 + l15;
      float w3 = W3s[c], bb = b2s[c];
#pragma unroll
      for (int rt = 0; rt < 4; ++rt) {
#pragma unroll
        for (int j = 0; j < 4; ++j) {
          int r = rt * 16 + l4 * 4 + j;
          float z2 = acc1[chunk][rt][ct][j] + bb;
          float sg = __builtin_amdgcn_rcpf(1.f + __expf(-z2));
          unsigned short u = f2b(w3 * sg);
          int bo = (c * 2) ^ ((r & 15) << 4);
          *reinterpret_cast<unsigned short*>(
              reinterpret_cast<char*>(buf) + r * 1024 + bo) = u;
        }
      }
    }
  }
  __syncthreads();

  // hoist this lane's (s0,s1) pairs for the 16 accumulator rows it owns
  float2 sv[16];
#pragma unroll
  for (int rt = 0; rt < 4; ++rt)
#pragma unroll
    for (int j = 0; j < 4; ++j) {
      int r = rt * 16 + l4 * 4 + j;
      sv[rt * 4 + j] = *reinterpret_cast<const float2*>(&st[r * 2]);
    }

  // ---- GEMM2: dh1 = dz2 @ W2^T ; dz1 = dh1*sigmoid(z1); ds = dz1 @ W1^T ----
  float p0[16], p1v[16];
#pragma unroll
  for (int i = 0; i < 16; ++i) { p0[i] = 0.f; p1v[i] = 0.f; }

  for (int chunk = 0; chunk < 2; ++chunk) {
    const int k0c = wid * 128 + chunk * 64;   // output h-columns
    f32x4 acc[4][4];
#pragma unroll
    for (int a = 0; a < 4; ++a)
#pragma unroll
      for (int b = 0; b < 4; ++b) acc[a][b] = fzero;

#pragma unroll 2
    for (int ct2 = 0; ct2 < 16; ++ct2) {   // reduction over c
      bf16x8 af[4];
      int bo = (ct2 * 64 + l4 * 16) ^ (l15 << 4);
#pragma unroll
      for (int rt = 0; rt < 4; ++rt) {
        int rr = rt * 16 + l15;
        af[rt] = __builtin_bit_cast(
            bf16x8, *reinterpret_cast<const int4*>(
                        reinterpret_cast<const char*>(buf) + rr * 1024 + bo));
      }
      bf16x8 bfr[4];
#pragma unroll
      for (int kt = 0; kt < 4; ++kt) {
        int frag = ct2 * 32 + (k0c >> 4) + kt;
        bfr[kt] = __builtin_bit_cast(
            bf16x8,
            *reinterpret_cast<const int4*>(packB2 + (frag * 64 + lane) * 8));
      }
#pragma unroll
      for (int rt = 0; rt < 4; ++rt)
#pragma unroll
        for (int kt = 0; kt < 4; ++kt)
          acc[rt][kt] = __builtin_amdgcn_mfma_f32_16x16x32_bf16(
              af[rt], bfr[kt], acc[rt][kt], 0, 0, 0);
    }
    // epilogue: sigmoid(z1) recomputed from state/W1/b1 (h1 was overwritten)
#pragma unroll
    for (int kt = 0; kt < 4; ++kt) {
      int kc = k0c + kt * 16 + l15;
      float w10 = W1s[kc], w11 = W1s[512 + kc], bb = b1s[kc];
#pragma unroll
      for (int rt = 0; rt < 4; ++rt) {
#pragma unroll
        for (int j = 0; j < 4; ++j) {
          float2 s = sv[rt * 4 + j];
          float z1 = fmaf(s.x, w10, fmaf(s.y, w11, bb));
          float sg = __builtin_amdgcn_rcpf(1.f + __expf(-z1));
          float dz1 = acc[rt][kt][j] * sg;
          p0[rt * 4 + j] = fmaf(dz1, w10, p0[rt * 4 + j]);
          p1v[rt * 4 + j] = fmaf(dz1, w11, p1v[rt * 4 + j]);
        }
      }
    }
  }

  // reduce partials across the 16 lanes of each row-group
#pragma unroll
  for (int i = 0; i < 16; ++i) {
    float a = p0[i], b = p1v[i];
    for (int m = 1; m < 16; m <<= 1) {
      a += __shfl_xor(a, m, 64);
      b += __shfl_xor(b, m, 64);
    }
    p0[i] = a;
    p1v[i] = b;
  }
  if (l15 == 0) {
#pragma unroll
    for (int rt = 0; rt < 4; ++rt)
#pragma unroll
      for (int j = 0; j < 4; ++j) {
        int r = rt * 16 + l4 * 4 + j;
        part[wid][r][0] = p0[rt * 4 + j];
        part[wid][r][1] = p1v[rt * 4 + j];
      }
  }
  __syncthreads();

  // ---- final: combine waves, damping + action term, write (B,2) ----
  if (t < 64) {
    long grow = row0 + t;
    float g0 = part[0][t][0] + part[1][t][0] + part[2][t][0] + part[3][t][0];
    float g1 = part[0][t][1] + part[1][t][1] + part[2][t][1] + part[3][t][1];
    const float4 ae0 = reinterpret_cast<const float4*>(action_emb)[grow * 2];
    const float4 ae1 = reinterpret_cast<const float4*>(action_emb)[grow * 2 + 1];
    float gu = Gb[0];
    gu = fmaf(ae0.x, Gw[0], gu);
    gu = fmaf(ae0.y, Gw[1], gu);
    gu = fmaf(ae0.z, Gw[2], gu);
    gu = fmaf(ae0.w, Gw[3], gu);
    gu = fmaf(ae1.x, Gw[4], gu);
    gu = fmaf(ae1.y, Gw[5], gu);
    gu = fmaf(ae1.z, Gw[6], gu);
    gu = fmaf(ae1.w, Gw[7], gu);
    float damping = __expf(log_damping[0]);
    float2 o;
    o.x = g1;                              // dq_dt = dH_dp
    o.y = -g0 - damping * g1 + gu;         // dp_dt
    reinterpret_cast<float2*>(out)[grow] = o;
  }
}

extern "C" void kernel_launch(void* const* d_in, const int* in_sizes, int n_in,
                              void* d_out, int out_size, void* d_ws,
                              size_t ws_size, hipStream_t stream) {
  // setup_inputs order: t, state, action_emb, W1, b1, W2, b2, W3, b3,
  //                     log_damping, Gw, Gb
  const float* state = (const float*)d_in[1];
  const float* action_emb = (const float*)d_in[2];
  const float* W1 = (const float*)d_in[3];
  const float* b1 = (const float*)d_in[4];
  const float* W2 = (const float*)d_in[5];
  const float* b2 = (const float*)d_in[6];
  const float* W3 = (const float*)d_in[7];
  const float* log_damping = (const float*)d_in[9];
  const float* Gw = (const float*)d_in[10];
  const float* Gb = (const float*)d_in[11];
  float* out = (float*)d_out;

  unsigned short* p1 = (unsigned short*)d_ws;       // 512KB packed W2
  unsigned short* p2 = p1 + 262144;                 // 512KB packed W2^T

  pack_w2_kernel<<<dim3(2048), dim3(256), 0, stream>>>(W2, p1, p2);
  phm_kernel<<<dim3(2048), dim3(256), 0, stream>>>(
      state, action_emb, W1, b1, b2, W3, log_damping, Gw, Gb, p1, p2, out);
}